// Round 4
// baseline (258.801 us; speedup 1.0000x reference)
//
#include <hip/hip_runtime.h>

typedef __attribute__((ext_vector_type(8))) short bf16x8;
typedef __attribute__((ext_vector_type(4))) float f32x4;
typedef __attribute__((ext_vector_type(4))) _Float16 f16x4;

static __device__ __forceinline__ unsigned short f32_to_bf16(float f) {
    unsigned int x = __float_as_uint(f);
    x += 0x7fffu + ((x >> 16) & 1u);   // round-to-nearest-even
    return (unsigned short)(x >> 16);
}

static constexpr int SMEM_BYTES = 21120;

// Cost volume as banded GEMM: out[n,j,h,x] = l̂[:,x]·r̂[:,x-j] = (l·r)·invl·invr.
// v4: TX=32 for all levels (TPW<=5 -> acc regs 20, VGPR cap 84 spill-free),
// launch_bounds(256,6) -> 6 blocks/CU; TPC=2 channel-split staging for L1/L2
// (partial ssq -> LDS psum, inv combined post-barrier, consumed only in the
// post-MFMA scale phase); f16 obuf still aliases the bf16 stage region.
template<int C, int H, int W, int D, int TX, int TPC>
__device__ __forceinline__
void cv_body(const int bx, const float* __restrict__ Lp, const float* __restrict__ Rp,
             float* __restrict__ out, char* smem)
{
    constexpr int NT = 256;
    constexpr int RS = TX + D;            // staged y range: [X0-D, X0+TX)
    constexpr int AS = C + 8;             // bf16 row stride (pad: conflict-free b128)
    constexpr int KC = C / 32;            // mfma k-steps
    constexpr int NSTRIP = TX / 16;       // 16-wide x-strips per block
    constexpr int WPS = (NT / 64) / NSTRIP;    // waves sharing one strip
    constexpr int NTT = D / 16 + 1;       // y-tiles per strip (exact band cover)
    constexpr int TPW = (NTT + WPS - 1) / WPS; // t-iterations per wave (reg accs)
    constexpr int COLS = TX + RS;         // staged spatial columns
    constexpr int CPT = C / TPC;          // channels per staging thread
    constexpr int STAGE_B = COLS * AS * 2;
    constexpr int OBUF_B  = D * TX * 2;   // f16, XOR-swizzled
    constexpr int UNION_B = STAGE_B > OBUF_B ? STAGE_B : OBUF_B;
    static_assert(UNION_B + COLS * 4 + TPC * COLS * 4 <= SMEM_BYTES, "lds budget");
    static_assert(COLS * TPC <= NT, "staging partition");
    static_assert(WPS * NSTRIP * 64 == NT, "wave partition");
    static_assert(C % (8 * TPC) == 0, "channel split granularity");

    unsigned short* Abf = (unsigned short*)smem;      // [RS][AS] raw r, bf16
    unsigned short* Bbf = Abf + RS * AS;              // [TX][AS] raw l, bf16
    char*  obuf = smem;                               // [D][TX] f16 (aliases stage)
    float* invA = (float*)(smem + UNION_B);           // [RS] 1/|r|  (non-aliased)
    float* invB = invA + RS;                          // [TX] 1/|l|
    float* psum = invB + TX;                          // [TPC][COLS] partial ssq

    const int tid = threadIdx.x;
    constexpr int NXB = W / TX;
    const int xb = bx % NXB;
    const int h  = (bx / NXB) % H;
    const int n  = bx / (NXB * H);
    const int X0 = xb * TX;

    const size_t CH = (size_t)H * W;
    const float* Lb = Lp + ((size_t)n * C * H + h) * W;
    const float* Rb = Rp + ((size_t)n * C * H + h) * W;

    // ---- stage: TPC threads per spatial column (channel-split), coalesced
    //      dword loads, raw->bf16 on the fly, partial ssq in fp32 ----
    if (tid < COLS * TPC) {
        const int sub = tid / COLS;       // channel-slice index
        const int col = tid % COLS;       // consecutive lanes -> consecutive cols
        const float* src; unsigned short* dst; int g;
        if (col < TX) { g = X0 + col;            src = Lb; dst = Bbf + col * AS; }
        else          { g = X0 - D + (col - TX); src = Rb; dst = Abf + (col - TX) * AS; }
        const bool zero = (col >= TX) && (g < 0);
        const int c0b = sub * CPT;
        float ssq = 0.f;
        if (!zero) {
            #pragma unroll
            for (int cc = 0; cc < CPT; cc += 8) {
                const int c0 = c0b + cc;
                float v[8];
                #pragma unroll
                for (int k = 0; k < 8; ++k) v[k] = src[(size_t)(c0 + k) * CH + g];
                union { unsigned short us[8]; uint4 q; } p;
                #pragma unroll
                for (int k = 0; k < 8; ++k) { ssq += v[k] * v[k]; p.us[k] = f32_to_bf16(v[k]); }
                *(uint4*)&dst[c0] = p.q;          // b128, conflict-free (AS pad)
            }
        } else {
            const uint4 z = {0u, 0u, 0u, 0u};
            #pragma unroll
            for (int cc = 0; cc < CPT; cc += 8) *(uint4*)&dst[c0b + cc] = z;
        }
        if (TPC == 1) {
            const float inv = 1.0f / fmaxf(sqrtf(ssq), 1e-12f);
            if (col < TX) invB[col] = inv; else invA[col - TX] = inv;
        } else {
            psum[sub * COLS + col] = ssq;
        }
    }
    __syncthreads();

    // combine partial ssq -> inv (writes non-aliased region; read only after
    // the NEXT barrier, in the scale phase)
    if (TPC > 1 && tid < COLS) {
        float s = 0.f;
        #pragma unroll
        for (int u = 0; u < TPC; ++u) s += psum[u * COLS + tid];
        const float inv = 1.0f / fmaxf(sqrtf(s), 1e-12f);
        if (tid < TX) invB[tid] = inv; else invA[tid - TX] = inv;
    }

    // ---- banded MFMA sweep, accumulators resident in registers ----
    const int wave = tid >> 6, lane = tid & 63;
    const int colc = lane & 15, quad = lane >> 4;
    const int strip = wave % NSTRIP;      // x-strip this wave serves
    const int tslc  = wave / NSTRIP;      // which slice of the t-range

    bf16x8 bfr[KC];
    #pragma unroll
    for (int kc = 0; kc < KC; ++kc)
        bfr[kc] = *(const bf16x8*)&Bbf[(strip * 16 + colc) * AS + kc * 32 + quad * 8];

    const int xl = strip * 16 + colc;

    f32x4 acc[TPW];
    #pragma unroll
    for (int tt = 0; tt < TPW; ++tt) {
        acc[tt] = {0.f, 0.f, 0.f, 0.f};
        const int t = tslc + tt * WPS;
        if (t < NTT) {
            const int yt = strip + t;
            #pragma unroll
            for (int kc = 0; kc < KC; ++kc) {
                const bf16x8 a =
                    *(const bf16x8*)&Abf[(yt * 16 + colc) * AS + kc * 32 + quad * 8];
                acc[tt] = __builtin_amdgcn_mfma_f32_16x16x32_bf16(a, bfr[kc], acc[tt], 0, 0, 0);
            }
        }
    }
    __syncthreads();          // stage reads done -> obuf may alias; inv visible

    // ---- scale after mfma, write f16 swizzled obuf ----
    const float sB = invB[xl];
    #pragma unroll
    for (int tt = 0; tt < TPW; ++tt) {
        const int t = tslc + tt * WPS;
        if (t < NTT) {
            const int yt = strip + t;
            const int yb = yt * 16 + quad * 4;
            const int jb = D + xl - yb;       // j = x - y (+D offset), row r
            #pragma unroll
            for (int r = 0; r < 4; ++r) {
                const int j = jb - r;
                if (j >= 0 && j < D) {
                    const float val = acc[tt][r] * sB * invA[yb + r];
                    *(_Float16*)(obuf + (((j * TX + xl) * 2) ^ ((j & 7) << 4))) = (_Float16)val;
                }
            }
        }
    }
    __syncthreads();

    // ---- coalesced nontemporal writeout ----
    constexpr int JV = TX / 4;
    constexpr int NIT = D * TX / 4 / NT;
    float* orow = out + ((size_t)n * D) * CH + (size_t)h * W + X0;
    #pragma unroll
    for (int it = 0; it < NIT; ++it) {
        const int idx = it * NT + tid;
        const int j = idx / JV, xo = idx % JV;
        const f16x4 hv = *(const f16x4*)(obuf + (((j * TX + xo * 4) * 2) ^ ((j & 7) << 4)));
        f32x4 o;
        o.x = (float)hv.x; o.y = (float)hv.y; o.z = (float)hv.z; o.w = (float)hv.w;
        __builtin_nontemporal_store(o, (f32x4*)&orow[(size_t)j * CH + xo * 4]);
    }
}

constexpr int G0 = 2 * 256 * (512 / 32);   // 8192
constexpr int G1 = 2 * 128 * (256 / 32);   // 2048
constexpr int G2 = 2 * 64  * (128 / 32);   // 512

static __device__ __forceinline__ int xcd_swz(int b, int nwg) {
    // bijective (nwg % 8 == 0): consecutive logical tiles land on one XCD's L2
    return (b & 7) * (nwg >> 3) + (b >> 3);
}

__global__ __launch_bounds__(256, 6)
void fused_cv(const float* __restrict__ l0, const float* __restrict__ r0, float* __restrict__ o0,
              const float* __restrict__ l1, const float* __restrict__ r1, float* __restrict__ o1,
              const float* __restrict__ l2, const float* __restrict__ r2, float* __restrict__ o2)
{
    __shared__ __align__(16) char smem[SMEM_BYTES];
    const int bid = blockIdx.x;
    if (bid < G0)
        cv_body<32, 256, 512, 128, 32, 1>(xcd_swz(bid, G0), l0, r0, o0, smem);
    else if (bid < G0 + G1)
        cv_body<64, 128, 256,  64, 32, 2>(xcd_swz(bid - G0, G1), l1, r1, o1, smem);
    else
        cv_body<96,  64, 128,  32, 32, 2>(xcd_swz(bid - G0 - G1, G2), l2, r2, o2, smem);
}

extern "C" void kernel_launch(void* const* d_in, const int* in_sizes, int n_in,
                              void* d_out, int out_size, void* d_ws, size_t ws_size,
                              hipStream_t stream) {
    (void)in_sizes; (void)n_in; (void)d_ws; (void)ws_size; (void)out_size;
    const float* l0 = (const float*)d_in[0];
    const float* r0 = (const float*)d_in[1];
    const float* l1 = (const float*)d_in[2];
    const float* r1 = (const float*)d_in[3];
    const float* l2 = (const float*)d_in[4];
    const float* r2 = (const float*)d_in[5];

    float* o0 = (float*)d_out;
    float* o1 = o0 + (size_t)2 * 128 * 256 * 512;
    float* o2 = o1 + (size_t)2 * 64 * 128 * 256;

    // Single fused launch: 10752 blocks x 256 thr, 21.1 KB LDS, VGPR<=84
    // -> 6 blocks/CU (24 waves).
    fused_cv<<<G0 + G1 + G2, 256, 0, stream>>>(l0, r0, o0, l1, r1, o1, l2, r2, o2);
}

// Round 5
// 254.335 us; speedup vs baseline: 1.0176x; 1.0176x over previous
//
#include <hip/hip_runtime.h>

typedef __attribute__((ext_vector_type(8))) short bf16x8;
typedef __attribute__((ext_vector_type(4))) float f32x4;
typedef __attribute__((ext_vector_type(4))) _Float16 f16x4;

static __device__ __forceinline__ unsigned short f32_to_bf16(float f) {
    unsigned int x = __float_as_uint(f);
    x += 0x7fffu + ((x >> 16) & 1u);   // round-to-nearest-even
    return (unsigned short)(x >> 16);
}

static constexpr int SMEM_BYTES = 21504;

// Cost volume as banded GEMM: out[n,j,h,x] = l̂[:,x]·r̂[:,x-j] = (l·r)·invl·invr.
// v5 = v3b (best-measured: TX=64 L0, reg accumulators, f16 obuf aliasing the
// bf16 stage, 21.5K LDS, (256,5)) + TPC=2 channel-split staging for L1/L2
// (halves stage load chains, full staging-thread utilization). Output stores
// nontemporal (pure stream).
template<int C, int H, int W, int D, int TX, int TPC>
__device__ __forceinline__
void cv_body(const int bx, const float* __restrict__ Lp, const float* __restrict__ Rp,
             float* __restrict__ out, char* smem)
{
    constexpr int NT = 256;
    constexpr int RS = TX + D;            // staged y range: [X0-D, X0+TX)
    constexpr int AS = C + 8;             // bf16 row stride (pad: conflict-free b128)
    constexpr int KC = C / 32;            // mfma k-steps
    constexpr int NSTRIP = TX / 16;       // 16-wide x-strips per block
    constexpr int WPS = (NT / 64) / NSTRIP;    // waves sharing one strip
    constexpr int NTT = D / 16 + 1;       // y-tiles per strip (exact band cover)
    constexpr int TPW = (NTT + WPS - 1) / WPS; // t-iterations per wave (reg accs)
    constexpr int COLS = TX + RS;         // staged spatial columns
    constexpr int CPT = C / TPC;          // channels per staging thread
    constexpr int STAGE_B = COLS * AS * 2;
    constexpr int OBUF_B  = D * TX * 2;   // f16, XOR-swizzled
    constexpr int UNION_B = STAGE_B > OBUF_B ? STAGE_B : OBUF_B;
    constexpr int PSUM_B  = (TPC > 1) ? TPC * COLS * 4 : 0;
    static_assert(UNION_B + COLS * 4 + PSUM_B <= SMEM_BYTES, "lds budget");
    static_assert(COLS * TPC <= NT, "staging partition");
    static_assert(WPS * NSTRIP * 64 == NT, "wave partition");
    static_assert(C % (8 * TPC) == 0, "channel split granularity");

    unsigned short* Abf = (unsigned short*)smem;      // [RS][AS] raw r, bf16
    unsigned short* Bbf = Abf + RS * AS;              // [TX][AS] raw l, bf16
    char*  obuf = smem;                               // [D][TX] f16 (aliases stage)
    float* invA = (float*)(smem + UNION_B);           // [RS] 1/|r|  (non-aliased)
    float* invB = invA + RS;                          // [TX] 1/|l|
    float* psum = invB + TX;                          // [TPC][COLS] partial ssq

    const int tid = threadIdx.x;
    constexpr int NXB = W / TX;
    const int xb = bx % NXB;
    const int h  = (bx / NXB) % H;
    const int n  = bx / (NXB * H);
    const int X0 = xb * TX;

    const size_t CH = (size_t)H * W;
    const float* Lb = Lp + ((size_t)n * C * H + h) * W;
    const float* Rb = Rp + ((size_t)n * C * H + h) * W;

    // ---- stage: TPC threads per spatial column (channel-split), coalesced
    //      dword loads, raw->bf16 on the fly, (partial) ssq in fp32 ----
    if (tid < COLS * TPC) {
        const int sub = tid / COLS;       // channel-slice index
        const int col = tid % COLS;       // consecutive lanes -> consecutive cols
        const float* src; unsigned short* dst; int g;
        if (col < TX) { g = X0 + col;            src = Lb; dst = Bbf + col * AS; }
        else          { g = X0 - D + (col - TX); src = Rb; dst = Abf + (col - TX) * AS; }
        const bool zero = (col >= TX) && (g < 0);
        const int c0b = sub * CPT;
        float ssq = 0.f;
        if (!zero) {
            #pragma unroll
            for (int cc = 0; cc < CPT; cc += 8) {
                const int c0 = c0b + cc;
                float v[8];
                #pragma unroll
                for (int k = 0; k < 8; ++k) v[k] = src[(size_t)(c0 + k) * CH + g];
                union { unsigned short us[8]; uint4 q; } p;
                #pragma unroll
                for (int k = 0; k < 8; ++k) { ssq += v[k] * v[k]; p.us[k] = f32_to_bf16(v[k]); }
                *(uint4*)&dst[c0] = p.q;          // b128, conflict-free (AS pad)
            }
        } else {
            const uint4 z = {0u, 0u, 0u, 0u};
            #pragma unroll
            for (int cc = 0; cc < CPT; cc += 8) *(uint4*)&dst[c0b + cc] = z;
        }
        if (TPC == 1) {
            const float inv = 1.0f / fmaxf(sqrtf(ssq), 1e-12f);
            if (col < TX) invB[col] = inv; else invA[col - TX] = inv;
        } else {
            psum[sub * COLS + col] = ssq;
        }
    }
    __syncthreads();

    // combine partial ssq -> inv (non-aliased region; consumed only after the
    // NEXT barrier, in the scale phase)
    if (TPC > 1 && tid < COLS) {
        float s = 0.f;
        #pragma unroll
        for (int u = 0; u < TPC; ++u) s += psum[u * COLS + tid];
        const float inv = 1.0f / fmaxf(sqrtf(s), 1e-12f);
        if (tid < TX) invB[tid] = inv; else invA[tid - TX] = inv;
    }

    // ---- banded MFMA sweep, accumulators resident in registers ----
    const int wave = tid >> 6, lane = tid & 63;
    const int colc = lane & 15, quad = lane >> 4;
    const int strip = wave % NSTRIP;      // x-strip this wave serves
    const int tslc  = wave / NSTRIP;      // which slice of the t-range

    bf16x8 bfr[KC];
    #pragma unroll
    for (int kc = 0; kc < KC; ++kc)
        bfr[kc] = *(const bf16x8*)&Bbf[(strip * 16 + colc) * AS + kc * 32 + quad * 8];

    const int xl = strip * 16 + colc;

    f32x4 acc[TPW];
    #pragma unroll
    for (int tt = 0; tt < TPW; ++tt) {
        acc[tt] = {0.f, 0.f, 0.f, 0.f};
        const int t = tslc + tt * WPS;
        if (t < NTT) {
            const int yt = strip + t;
            #pragma unroll
            for (int kc = 0; kc < KC; ++kc) {
                const bf16x8 a =
                    *(const bf16x8*)&Abf[(yt * 16 + colc) * AS + kc * 32 + quad * 8];
                acc[tt] = __builtin_amdgcn_mfma_f32_16x16x32_bf16(a, bfr[kc], acc[tt], 0, 0, 0);
            }
        }
    }
    __syncthreads();          // stage reads done -> obuf may alias; inv visible

    // ---- scale after mfma, write f16 swizzled obuf ----
    const float sB = invB[xl];
    #pragma unroll
    for (int tt = 0; tt < TPW; ++tt) {
        const int t = tslc + tt * WPS;
        if (t < NTT) {
            const int yt = strip + t;
            const int yb = yt * 16 + quad * 4;
            const int jb = D + xl - yb;       // j = x - y (+D offset), row r
            #pragma unroll
            for (int r = 0; r < 4; ++r) {
                const int j = jb - r;
                if (j >= 0 && j < D) {
                    const float val = acc[tt][r] * sB * invA[yb + r];
                    *(_Float16*)(obuf + (((j * TX + xl) * 2) ^ ((j & 7) << 4))) = (_Float16)val;
                }
            }
        }
    }
    __syncthreads();

    // ---- coalesced nontemporal writeout ----
    constexpr int JV = TX / 4;
    constexpr int NIT = D * TX / 4 / NT;
    float* orow = out + ((size_t)n * D) * CH + (size_t)h * W + X0;
    #pragma unroll
    for (int it = 0; it < NIT; ++it) {
        const int idx = it * NT + tid;
        const int j = idx / JV, xo = idx % JV;
        const f16x4 hv = *(const f16x4*)(obuf + (((j * TX + xo * 4) * 2) ^ ((j & 7) << 4)));
        f32x4 o;
        o.x = (float)hv.x; o.y = (float)hv.y; o.z = (float)hv.z; o.w = (float)hv.w;
        __builtin_nontemporal_store(o, (f32x4*)&orow[(size_t)j * CH + xo * 4]);
    }
}

constexpr int G0 = 2 * 256 * (512 / 64);   // 4096 (TX=64)
constexpr int G1 = 2 * 128 * (256 / 32);   // 2048 (TX=32)
constexpr int G2 = 2 * 64  * (128 / 32);   // 512  (TX=32)

static __device__ __forceinline__ int xcd_swz(int b, int nwg) {
    // bijective (nwg % 8 == 0): consecutive logical tiles land on one XCD's L2
    return (b & 7) * (nwg >> 3) + (b >> 3);
}

__global__ __launch_bounds__(256, 5)
void fused_cv(const float* __restrict__ l0, const float* __restrict__ r0, float* __restrict__ o0,
              const float* __restrict__ l1, const float* __restrict__ r1, float* __restrict__ o1,
              const float* __restrict__ l2, const float* __restrict__ r2, float* __restrict__ o2)
{
    __shared__ __align__(16) char smem[SMEM_BYTES];
    const int bid = blockIdx.x;
    if (bid < G0)
        cv_body<32, 256, 512, 128, 64, 1>(xcd_swz(bid, G0), l0, r0, o0, smem);
    else if (bid < G0 + G1)
        cv_body<64, 128, 256,  64, 32, 2>(xcd_swz(bid - G0, G1), l1, r1, o1, smem);
    else
        cv_body<96,  64, 128,  32, 32, 2>(xcd_swz(bid - G0 - G1, G2), l2, r2, o2, smem);
}

extern "C" void kernel_launch(void* const* d_in, const int* in_sizes, int n_in,
                              void* d_out, int out_size, void* d_ws, size_t ws_size,
                              hipStream_t stream) {
    (void)in_sizes; (void)n_in; (void)d_ws; (void)ws_size; (void)out_size;
    const float* l0 = (const float*)d_in[0];
    const float* r0 = (const float*)d_in[1];
    const float* l1 = (const float*)d_in[2];
    const float* r1 = (const float*)d_in[3];
    const float* l2 = (const float*)d_in[4];
    const float* r2 = (const float*)d_in[5];

    float* o0 = (float*)d_out;
    float* o1 = o0 + (size_t)2 * 128 * 256 * 512;
    float* o2 = o1 + (size_t)2 * 64 * 128 * 256;

    // Single fused launch: 6656 blocks x 256 thr, 21.5 KB LDS -> 5 blocks/CU.
    fused_cv<<<G0 + G1 + G2, 256, 0, stream>>>(l0, r0, o0, l1, r1, o1, l2, r2, o2);
}